// Round 1
// baseline (559.517 us; speedup 1.0000x reference)
//
#include <hip/hip_runtime.h>

typedef __attribute__((ext_vector_type(8))) short short8;
typedef __attribute__((ext_vector_type(4))) float f32x4;

__device__ __forceinline__ unsigned short f2bf(float f) {
  union { float f; unsigned u; } v; v.f = f;
  unsigned r = v.u + 0x7FFFu + ((v.u >> 16) & 1u);
  return (unsigned short)(r >> 16);
}
__device__ __forceinline__ float bf2f(unsigned short h) {
  union { unsigned u; float f; } v; v.u = ((unsigned)h) << 16;
  return v.f;
}

// ---------------- cast fp32 -> bf16 (vectorized) ----------------
__global__ void cast_f32_bf16(const float* __restrict__ in, unsigned short* __restrict__ out, int n4) {
  int i = blockIdx.x * blockDim.x + threadIdx.x;
  if (i >= n4) return;
  float4 v = ((const float4*)in)[i];
  ushort4 o;
  o.x = f2bf(v.x); o.y = f2bf(v.y); o.z = f2bf(v.z); o.w = f2bf(v.w);
  ((ushort4*)out)[i] = o;
}

// ---------------- transpose + cast: in (K x N) fp32 -> out (N x K) bf16 ----------------
__global__ void transpose_cast(const float* __restrict__ in, unsigned short* __restrict__ out, int K, int N) {
  __shared__ float tile[32][33];
  int n0 = blockIdx.x * 32, k0 = blockIdx.y * 32;
  int x = threadIdx.x, y = threadIdx.y;  // 32 x 8
#pragma unroll
  for (int j = 0; j < 4; ++j) tile[y + 8 * j][x] = in[(size_t)(k0 + y + 8 * j) * N + n0 + x];
  __syncthreads();
#pragma unroll
  for (int j = 0; j < 4; ++j) out[(size_t)(n0 + y + 8 * j) * K + k0 + x] = f2bf(tile[x][y + 8 * j]);
}

// ---------------- GEMM: C(MxN) = A(MxK,bf16) * Bt(NxK,bf16)^T ; m97 structure ----------------
template <int OUT_BF16>
__global__ __launch_bounds__(256, 2) void gemm_bt(const unsigned short* __restrict__ A,
                                                  const unsigned short* __restrict__ Bt,
                                                  void* __restrict__ Cv, int K, int ldc) {
  __shared__ alignas(16) unsigned short As[128 * 32];
  __shared__ alignas(16) unsigned short Bs[128 * 32];
  const int t = threadIdx.x;
  const int lane = t & 63, w = t >> 6;
  const int l15 = lane & 15, quad = lane >> 4;
  const int bn0 = blockIdx.x * 128, bm0 = blockIdx.y * 128;
  const int wm = (w >> 1) * 64, wn = (w & 1) * 64;
  const unsigned short* Ab = A + (size_t)bm0 * K;
  const unsigned short* Bb = Bt + (size_t)bn0 * K;

  f32x4 acc[4][4];
  const f32x4 zf = {0.f, 0.f, 0.f, 0.f};
#pragma unroll
  for (int i = 0; i < 4; ++i)
#pragma unroll
    for (int j = 0; j < 4; ++j) acc[i][j] = zf;

  for (int k0 = 0; k0 < K; k0 += 32) {
    __syncthreads();
#pragma unroll
    for (int r = 0; r < 2; ++r) {
      int e = r * 256 + t;
      const unsigned short* ga = Ab + (size_t)(e >> 2) * K + k0 + (e & 3) * 8;
      __builtin_amdgcn_global_load_lds((const __attribute__((address_space(1))) void*)ga,
                                       (__attribute__((address_space(3))) void*)(As + e * 8), 16, 0, 0);
      const unsigned short* gb = Bb + (size_t)(e >> 2) * K + k0 + (e & 3) * 8;
      __builtin_amdgcn_global_load_lds((const __attribute__((address_space(1))) void*)gb,
                                       (__attribute__((address_space(3))) void*)(Bs + e * 8), 16, 0, 0);
    }
    __syncthreads();
    short8 af[4], bf[4];
#pragma unroll
    for (int i = 0; i < 4; ++i)
      af[i] = *reinterpret_cast<const short8*>(As + (wm + i * 16 + l15) * 32 + quad * 8);
#pragma unroll
    for (int j = 0; j < 4; ++j)
      bf[j] = *reinterpret_cast<const short8*>(Bs + (wn + j * 16 + l15) * 32 + quad * 8);
#pragma unroll
    for (int i = 0; i < 4; ++i)
#pragma unroll
      for (int j = 0; j < 4; ++j)
        acc[i][j] = __builtin_amdgcn_mfma_f32_16x16x32_bf16(af[i], bf[j], acc[i][j], 0, 0, 0);
  }
#pragma unroll
  for (int i = 0; i < 4; ++i)
#pragma unroll
    for (int j = 0; j < 4; ++j)
#pragma unroll
      for (int r = 0; r < 4; ++r) {
        size_t row = (size_t)(bm0 + wm + i * 16 + quad * 4 + r);
        size_t col = (size_t)(bn0 + wn + j * 16 + l15);
        if (OUT_BF16)
          ((unsigned short*)Cv)[row * ldc + col] = f2bf(acc[i][j][r]);
        else
          ((float*)Cv)[row * ldc + col] = acc[i][j][r];
      }
}

// ---------------- RoPE in-place on qkv (Q cols 0..2047, K cols 2048..2559) ----------------
__global__ void rope_kernel(unsigned short* __restrict__ qkv, const float* __restrict__ fcos,
                            const float* __restrict__ fsin) {
  int tid = blockIdx.x * 256 + threadIdx.x;  // 4096 * 1280 threads
  int p = tid % 1280;
  int row = tid / 1280;
  int col = (p < 1024) ? (p * 2) : (2048 + (p - 1024) * 2);
  int s = row & 2047;
  int fi = (col & 63) >> 1;
  float c = fcos[s * 32 + fi], sn = fsin[s * 32 + fi];
  unsigned int* ptr = (unsigned int*)(qkv + (size_t)row * 3072 + col);
  unsigned int pr = *ptr;
  float xr = bf2f((unsigned short)(pr & 0xFFFFu));
  float xi = bf2f((unsigned short)(pr >> 16));
  float orr = xr * c - xi * sn;
  float oi = xr * sn + xi * c;
  *ptr = ((unsigned)f2bf(oi) << 16) | (unsigned)f2bf(orr);
}

// ---------------- flash attention: 64 q-rows/block, 4 waves x 16 rows ----------------
__global__ __launch_bounds__(256, 2) void flash_attn(const unsigned short* __restrict__ qkv,
                                                     unsigned short* __restrict__ out) {
  __shared__ alignas(16) unsigned short Ks[64 * 72];  // [kv][d], stride 72 (144B, 16B aligned)
  __shared__ alignas(16) unsigned short Vt[64 * 72];  // [d][kv]
  __shared__ alignas(16) unsigned short Ps[64 * 72];  // per-wave 16-row regions, [qrow][kv]
  const int t = threadIdx.x, lane = t & 63, w = t >> 6;
  const int l15 = lane & 15, quad = lane >> 4;
  const int qb = blockIdx.x, h = blockIdx.y, b = blockIdx.z;
  const int kvh = h >> 2;
  const size_t rowB = (size_t)b * 2048;
  const unsigned short* Qg = qkv + (rowB + (size_t)qb * 64) * 3072 + h * 64;
  const unsigned short* Kg = qkv + rowB * 3072 + 2048 + kvh * 64;
  const unsigned short* Vg = qkv + rowB * 3072 + 2560 + kvh * 64;

  // Q A-fragments for this wave: m = l15 (q row within wave's 16), k = s*32 + quad*8 + j
  short8 qf[2];
#pragma unroll
  for (int s = 0; s < 2; ++s)
    qf[s] = *reinterpret_cast<const short8*>(Qg + (size_t)(w * 16 + l15) * 3072 + s * 32 + quad * 8);

  const f32x4 zf = {0.f, 0.f, 0.f, 0.f};
  f32x4 oacc[4];
#pragma unroll
  for (int j = 0; j < 4; ++j) oacc[j] = zf;
  float mrun[4], lrun[4];
#pragma unroll
  for (int r = 0; r < 4; ++r) { mrun[r] = -1e30f; lrun[r] = 0.f; }

  for (int kb = 0; kb <= qb; ++kb) {
    __syncthreads();
    // stage K tile [kv][d] and V tile transposed [d][kv]
#pragma unroll
    for (int r = 0; r < 2; ++r) {
      int e = r * 256 + t, row = e >> 3, c = e & 7;
      *reinterpret_cast<short8*>(Ks + row * 72 + c * 8) =
          *reinterpret_cast<const short8*>(Kg + (size_t)(kb * 64 + row) * 3072 + c * 8);
      short8 v = *reinterpret_cast<const short8*>(Vg + (size_t)(kb * 64 + row) * 3072 + c * 8);
#pragma unroll
      for (int x2 = 0; x2 < 8; ++x2) Vt[(c * 8 + x2) * 72 + row] = (unsigned short)v[x2];
    }
    __syncthreads();

    // S = Q K^T (this wave's 16 q-rows x 64 kv-cols)
    f32x4 sc[4];
#pragma unroll
    for (int j = 0; j < 4; ++j) sc[j] = zf;
#pragma unroll
    for (int s = 0; s < 2; ++s)
#pragma unroll
      for (int j = 0; j < 4; ++j) {
        short8 kf = *reinterpret_cast<const short8*>(Ks + (j * 16 + l15) * 72 + s * 32 + quad * 8);
        sc[j] = __builtin_amdgcn_mfma_f32_16x16x32_bf16(qf[s], kf, sc[j], 0, 0, 0);
      }

    // scale + causal mask + row max (C layout: row = quad*4+r, col = j*16+l15)
    const int qr0 = qb * 64 + w * 16 + quad * 4;
    float bmax[4] = {-1e30f, -1e30f, -1e30f, -1e30f};
#pragma unroll
    for (int j = 0; j < 4; ++j) {
      int kg = kb * 64 + j * 16 + l15;
#pragma unroll
      for (int r = 0; r < 4; ++r) {
        float v = sc[j][r] * 0.125f;
        v = (kg > qr0 + r) ? -1e30f : v;
        sc[j][r] = v;
        bmax[r] = fmaxf(bmax[r], v);
      }
    }
#pragma unroll
    for (int m = 1; m < 16; m <<= 1)
#pragma unroll
      for (int r = 0; r < 4; ++r) bmax[r] = fmaxf(bmax[r], __shfl_xor(bmax[r], m, 64));

    float alpha[4], bsum[4] = {0.f, 0.f, 0.f, 0.f};
#pragma unroll
    for (int r = 0; r < 4; ++r) {
      float mnew = fmaxf(mrun[r], bmax[r]);
      alpha[r] = __expf(mrun[r] - mnew);
      mrun[r] = mnew;
    }
#pragma unroll
    for (int j = 0; j < 4; ++j)
#pragma unroll
      for (int r = 0; r < 4; ++r) {
        float p = __expf(sc[j][r] - mrun[r]);
        sc[j][r] = p;
        bsum[r] += p;
      }
#pragma unroll
    for (int m = 1; m < 16; m <<= 1)
#pragma unroll
      for (int r = 0; r < 4; ++r) bsum[r] += __shfl_xor(bsum[r], m, 64);
#pragma unroll
    for (int r = 0; r < 4; ++r) lrun[r] = lrun[r] * alpha[r] + bsum[r];

    // rescale O, spill P (C layout) to LDS for A-layout reload
#pragma unroll
    for (int j = 0; j < 4; ++j)
#pragma unroll
      for (int r = 0; r < 4; ++r) {
        oacc[j][r] *= alpha[r];
        Ps[(w * 16 + quad * 4 + r) * 72 + j * 16 + l15] = f2bf(sc[j][r]);
      }

    // O += P V  (A: m=l15, k=quad*8+j ; B from Vt[d][kv])
#pragma unroll
    for (int s = 0; s < 2; ++s) {
      short8 pf = *reinterpret_cast<const short8*>(Ps + (w * 16 + l15) * 72 + s * 32 + quad * 8);
#pragma unroll
      for (int j = 0; j < 4; ++j) {
        short8 vf = *reinterpret_cast<const short8*>(Vt + (j * 16 + l15) * 72 + s * 32 + quad * 8);
        oacc[j] = __builtin_amdgcn_mfma_f32_16x16x32_bf16(pf, vf, oacc[j], 0, 0, 0);
      }
    }
  }

#pragma unroll
  for (int j = 0; j < 4; ++j)
#pragma unroll
    for (int r = 0; r < 4; ++r) {
      size_t row = rowB + (size_t)qb * 64 + w * 16 + quad * 4 + r;
      size_t col = (size_t)h * 64 + j * 16 + l15;
      out[row * 2048 + col] = f2bf(oacc[j][r] / lrun[r]);
    }
}

extern "C" void kernel_launch(void* const* d_in, const int* in_sizes, int n_in, void* d_out,
                              int out_size, void* d_ws, size_t ws_size, hipStream_t stream) {
  const float* x = (const float*)d_in[0];
  const float* fcos = (const float*)d_in[1];
  const float* fsin = (const float*)d_in[2];
  const float* wq = (const float*)d_in[3];
  const float* wk = (const float*)d_in[4];
  const float* wv = (const float*)d_in[5];
  const float* wo = (const float*)d_in[6];

  char* ws = (char*)d_ws;
  unsigned short* xb = (unsigned short*)ws;                          // 4096x2048 bf16 : 16 MiB
  unsigned short* wt = (unsigned short*)(ws + 16777216ull);          // 3072x2048 bf16 (wq^T|wk^T|wv^T)
  unsigned short* wot = (unsigned short*)(ws + 29360128ull);         // 2048x2048 bf16
  unsigned short* qkv = (unsigned short*)(ws + 37748736ull);         // 4096x3072 bf16
  unsigned short* attno = (unsigned short*)(ws + 62914560ull);       // 4096x2048 bf16
  // total ws use: 79,691,776 bytes

  cast_f32_bf16<<<8192, 256, 0, stream>>>(x, xb, 2097152);
  transpose_cast<<<dim3(64, 64), dim3(32, 8), 0, stream>>>(wq, wt, 2048, 2048);
  transpose_cast<<<dim3(16, 64), dim3(32, 8), 0, stream>>>(wk, wt + 2048ull * 2048, 2048, 512);
  transpose_cast<<<dim3(16, 64), dim3(32, 8), 0, stream>>>(wv, wt + 2560ull * 2048, 2048, 512);
  transpose_cast<<<dim3(64, 64), dim3(32, 8), 0, stream>>>(wo, wot, 2048, 2048);

  // QKV: [4096 x 3072] = xb [4096x2048] @ [wq|wk|wv]
  gemm_bt<1><<<dim3(24, 32), 256, 0, stream>>>(xb, wt, qkv, 2048, 3072);
  rope_kernel<<<20480, 256, 0, stream>>>(qkv, fcos, fsin);
  flash_attn<<<dim3(32, 32, 2), 256, 0, stream>>>(qkv, attno);
  // out = attno @ wo  (fp32 out)
  gemm_bt<0><<<dim3(16, 32), 256, 0, stream>>>(attno, wot, d_out, 2048, 2048);
}

// Round 2
// 500.283 us; speedup vs baseline: 1.1184x; 1.1184x over previous
//
#include <hip/hip_runtime.h>

typedef __attribute__((ext_vector_type(8))) short short8;
typedef __attribute__((ext_vector_type(4))) float f32x4;

__device__ __forceinline__ unsigned short f2bf(float f) {
  union { float f; unsigned u; } v; v.f = f;
  unsigned r = v.u + 0x7FFFu + ((v.u >> 16) & 1u);
  return (unsigned short)(r >> 16);
}
__device__ __forceinline__ float bf2f(unsigned short h) {
  union { unsigned u; float f; } v; v.u = ((unsigned)h) << 16;
  return v.f;
}

// ---------------- cast fp32 -> bf16 (vectorized) ----------------
__global__ void cast_f32_bf16(const float* __restrict__ in, unsigned short* __restrict__ out, int n4) {
  int i = blockIdx.x * blockDim.x + threadIdx.x;
  if (i >= n4) return;
  float4 v = ((const float4*)in)[i];
  ushort4 o;
  o.x = f2bf(v.x); o.y = f2bf(v.y); o.z = f2bf(v.z); o.w = f2bf(v.w);
  ((ushort4*)out)[i] = o;
}

// ---------------- transpose + cast: in (K x N) fp32 -> out (N x K) bf16 ----------------
__global__ void transpose_cast(const float* __restrict__ in, unsigned short* __restrict__ out, int K, int N) {
  __shared__ float tile[32][33];
  int n0 = blockIdx.x * 32, k0 = blockIdx.y * 32;
  int x = threadIdx.x, y = threadIdx.y;  // 32 x 8
#pragma unroll
  for (int j = 0; j < 4; ++j) tile[y + 8 * j][x] = in[(size_t)(k0 + y + 8 * j) * N + n0 + x];
  __syncthreads();
#pragma unroll
  for (int j = 0; j < 4; ++j) out[(size_t)(n0 + y + 8 * j) * K + k0 + x] = f2bf(tile[x][y + 8 * j]);
}

// ---------------- V transpose: qkv V-slice [4096 x 512] -> vt [b][kvh][d][s] ----------------
// out index for (row=b*2048+s, col=kvh*64+d): ((b*8+kvh)*64+d)*2048 + s
__global__ void v_transpose(const unsigned short* __restrict__ qkv, unsigned short* __restrict__ vt) {
  __shared__ unsigned short tile[32][33];
  int c0 = blockIdx.x * 32, r0 = blockIdx.y * 32;
  int x = threadIdx.x, y = threadIdx.y;  // 32 x 8
#pragma unroll
  for (int j = 0; j < 4; ++j)
    tile[y + 8 * j][x] = qkv[(size_t)(r0 + y + 8 * j) * 3072 + 2560 + c0 + x];
  __syncthreads();
  int b = r0 >> 11;        // constant per tile
  int kvh = c0 >> 6;       // constant per tile
#pragma unroll
  for (int j = 0; j < 4; ++j) {
    int c = c0 + y + 8 * j, r = r0 + x;
    vt[((size_t)(b * 8 + kvh) * 64 + (c & 63)) * 2048 + (r & 2047)] = tile[x][y + 8 * j];
  }
}

// ---------------- GEMM: C(MxN) = A(MxK,bf16) * Bt(NxK,bf16)^T ; m97 structure ----------------
template <int OUT_BF16>
__global__ __launch_bounds__(256, 2) void gemm_bt(const unsigned short* __restrict__ A,
                                                  const unsigned short* __restrict__ Bt,
                                                  void* __restrict__ Cv, int K, int ldc) {
  __shared__ alignas(16) unsigned short As[128 * 32];
  __shared__ alignas(16) unsigned short Bs[128 * 32];
  const int t = threadIdx.x;
  const int lane = t & 63, w = t >> 6;
  const int l15 = lane & 15, quad = lane >> 4;
  const int bn0 = blockIdx.x * 128, bm0 = blockIdx.y * 128;
  const int wm = (w >> 1) * 64, wn = (w & 1) * 64;
  const unsigned short* Ab = A + (size_t)bm0 * K;
  const unsigned short* Bb = Bt + (size_t)bn0 * K;

  f32x4 acc[4][4];
  const f32x4 zf = {0.f, 0.f, 0.f, 0.f};
#pragma unroll
  for (int i = 0; i < 4; ++i)
#pragma unroll
    for (int j = 0; j < 4; ++j) acc[i][j] = zf;

  for (int k0 = 0; k0 < K; k0 += 32) {
    __syncthreads();
#pragma unroll
    for (int r = 0; r < 2; ++r) {
      int e = r * 256 + t;
      const unsigned short* ga = Ab + (size_t)(e >> 2) * K + k0 + (e & 3) * 8;
      __builtin_amdgcn_global_load_lds((const __attribute__((address_space(1))) void*)ga,
                                       (__attribute__((address_space(3))) void*)(As + e * 8), 16, 0, 0);
      const unsigned short* gb = Bb + (size_t)(e >> 2) * K + k0 + (e & 3) * 8;
      __builtin_amdgcn_global_load_lds((const __attribute__((address_space(1))) void*)gb,
                                       (__attribute__((address_space(3))) void*)(Bs + e * 8), 16, 0, 0);
    }
    __syncthreads();
    short8 af[4], bf[4];
#pragma unroll
    for (int i = 0; i < 4; ++i)
      af[i] = *reinterpret_cast<const short8*>(As + (wm + i * 16 + l15) * 32 + quad * 8);
#pragma unroll
    for (int j = 0; j < 4; ++j)
      bf[j] = *reinterpret_cast<const short8*>(Bs + (wn + j * 16 + l15) * 32 + quad * 8);
#pragma unroll
    for (int i = 0; i < 4; ++i)
#pragma unroll
      for (int j = 0; j < 4; ++j)
        acc[i][j] = __builtin_amdgcn_mfma_f32_16x16x32_bf16(af[i], bf[j], acc[i][j], 0, 0, 0);
  }
#pragma unroll
  for (int i = 0; i < 4; ++i)
#pragma unroll
    for (int j = 0; j < 4; ++j)
#pragma unroll
      for (int r = 0; r < 4; ++r) {
        size_t row = (size_t)(bm0 + wm + i * 16 + quad * 4 + r);
        size_t col = (size_t)(bn0 + wn + j * 16 + l15);
        if (OUT_BF16)
          ((unsigned short*)Cv)[row * ldc + col] = f2bf(acc[i][j][r]);
        else
          ((float*)Cv)[row * ldc + col] = acc[i][j][r];
      }
}

// ---------------- RoPE in-place on qkv (Q cols 0..2047, K cols 2048..2559) ----------------
__global__ void rope_kernel(unsigned short* __restrict__ qkv, const float* __restrict__ fcos,
                            const float* __restrict__ fsin) {
  int tid = blockIdx.x * 256 + threadIdx.x;  // 4096 * 1280 threads
  int p = tid % 1280;
  int row = tid / 1280;
  int col = (p < 1024) ? (p * 2) : (2048 + (p - 1024) * 2);
  int s = row & 2047;
  int fi = (col & 63) >> 1;
  float c = fcos[s * 32 + fi], sn = fsin[s * 32 + fi];
  unsigned int* ptr = (unsigned int*)(qkv + (size_t)row * 3072 + col);
  unsigned int pr = *ptr;
  float xr = bf2f((unsigned short)(pr & 0xFFFFu));
  float xi = bf2f((unsigned short)(pr >> 16));
  float orr = xr * c - xi * sn;
  float oi = xr * sn + xi * c;
  *ptr = ((unsigned)f2bf(oi) << 16) | (unsigned)f2bf(orr);
}

// ---------------- flash attention: 64 q-rows/block, 4 waves x 16 rows ----------------
// V comes pre-transposed: vt [b][kvh][d=64][s=2048]
__global__ __launch_bounds__(256, 2) void flash_attn(const unsigned short* __restrict__ qkv,
                                                     const unsigned short* __restrict__ vt,
                                                     unsigned short* __restrict__ out) {
  __shared__ alignas(16) unsigned short Ks[64 * 72];  // [kv][d], stride 72
  __shared__ alignas(16) unsigned short Vs[64 * 72];  // [d][kv], stride 72
  __shared__ alignas(16) unsigned short Ps[64 * 72];  // [qrow][kv]
  const int t = threadIdx.x, lane = t & 63, w = t >> 6;
  const int l15 = lane & 15, quad = lane >> 4;
  const int qb = (int)gridDim.x - 1 - (int)blockIdx.x;  // longest blocks first
  const int h = blockIdx.y, b = blockIdx.z;
  const int kvh = h >> 2;
  const size_t rowB = (size_t)b * 2048;
  const unsigned short* Qg = qkv + (rowB + (size_t)qb * 64) * 3072 + h * 64;
  const unsigned short* Kg = qkv + rowB * 3072 + 2048 + kvh * 64;
  const unsigned short* Vtg = vt + (size_t)(b * 8 + kvh) * 64 * 2048;  // [d][s]

  // log2-domain scale: 1/sqrt(64) * log2(e)
  const float SC = 0.18033688011112042f;

  short8 qf[2];
#pragma unroll
  for (int s = 0; s < 2; ++s)
    qf[s] = *reinterpret_cast<const short8*>(Qg + (size_t)(w * 16 + l15) * 3072 + s * 32 + quad * 8);

  const f32x4 zf = {0.f, 0.f, 0.f, 0.f};
  f32x4 oacc[4];
#pragma unroll
  for (int j = 0; j < 4; ++j) oacc[j] = zf;
  float mrun[4], lrun[4];
#pragma unroll
  for (int r = 0; r < 4; ++r) { mrun[r] = -1e30f; lrun[r] = 0.f; }

  for (int kb = 0; kb <= qb; ++kb) {
    const bool diag = (kb == qb);
    __syncthreads();
    // stage K tile [kv][d] and pre-transposed V tile [d][kv] — all b128, conflict-free
#pragma unroll
    for (int r = 0; r < 2; ++r) {
      int e = r * 256 + t, row = e >> 3, c8 = (e & 7) * 8;
      *reinterpret_cast<short8*>(Ks + row * 72 + c8) =
          *reinterpret_cast<const short8*>(Kg + (size_t)(kb * 64 + row) * 3072 + c8);
      *reinterpret_cast<short8*>(Vs + row * 72 + c8) =
          *reinterpret_cast<const short8*>(Vtg + (size_t)row * 2048 + kb * 64 + c8);
    }
    __syncthreads();

    // S = Q K^T (this wave's 16 q-rows x 64 kv-cols)
    f32x4 sc[4];
#pragma unroll
    for (int j = 0; j < 4; ++j) sc[j] = zf;
#pragma unroll
    for (int s = 0; s < 2; ++s)
#pragma unroll
      for (int j = 0; j < 4; ++j) {
        short8 kf = *reinterpret_cast<const short8*>(Ks + (j * 16 + l15) * 72 + s * 32 + quad * 8);
        sc[j] = __builtin_amdgcn_mfma_f32_16x16x32_bf16(qf[s], kf, sc[j], 0, 0, 0);
      }

    // scale (+ diagonal-only causal mask) + row max
    const int qr0 = qb * 64 + w * 16 + quad * 4;
    float bmax[4] = {-1e30f, -1e30f, -1e30f, -1e30f};
#pragma unroll
    for (int j = 0; j < 4; ++j) {
      int kg = kb * 64 + j * 16 + l15;
#pragma unroll
      for (int r = 0; r < 4; ++r) {
        float v = sc[j][r] * SC;
        if (diag) v = (kg > qr0 + r) ? -1e30f : v;
        sc[j][r] = v;
        bmax[r] = fmaxf(bmax[r], v);
      }
    }
#pragma unroll
    for (int m = 1; m < 16; m <<= 1)
#pragma unroll
      for (int r = 0; r < 4; ++r) bmax[r] = fmaxf(bmax[r], __shfl_xor(bmax[r], m, 64));

    float alpha[4], bsum[4] = {0.f, 0.f, 0.f, 0.f};
#pragma unroll
    for (int r = 0; r < 4; ++r) {
      float mnew = fmaxf(mrun[r], bmax[r]);
      alpha[r] = exp2f(mrun[r] - mnew);
      mrun[r] = mnew;
    }
#pragma unroll
    for (int j = 0; j < 4; ++j)
#pragma unroll
      for (int r = 0; r < 4; ++r) {
        float p = exp2f(sc[j][r] - mrun[r]);
        sc[j][r] = p;
        bsum[r] += p;
      }
#pragma unroll
    for (int m = 1; m < 16; m <<= 1)
#pragma unroll
      for (int r = 0; r < 4; ++r) bsum[r] += __shfl_xor(bsum[r], m, 64);
#pragma unroll
    for (int r = 0; r < 4; ++r) lrun[r] = lrun[r] * alpha[r] + bsum[r];

    // rescale O, spill P (C layout) to LDS for A-layout reload
#pragma unroll
    for (int j = 0; j < 4; ++j)
#pragma unroll
      for (int r = 0; r < 4; ++r) {
        oacc[j][r] *= alpha[r];
        Ps[(w * 16 + quad * 4 + r) * 72 + j * 16 + l15] = f2bf(sc[j][r]);
      }

    // O += P V  (A: m=l15, k=quad*8+j ; B from Vs[d][kv])
#pragma unroll
    for (int s = 0; s < 2; ++s) {
      short8 pf = *reinterpret_cast<const short8*>(Ps + (w * 16 + l15) * 72 + s * 32 + quad * 8);
#pragma unroll
      for (int j = 0; j < 4; ++j) {
        short8 vf = *reinterpret_cast<const short8*>(Vs + (j * 16 + l15) * 72 + s * 32 + quad * 8);
        oacc[j] = __builtin_amdgcn_mfma_f32_16x16x32_bf16(pf, vf, oacc[j], 0, 0, 0);
      }
    }
  }

#pragma unroll
  for (int j = 0; j < 4; ++j)
#pragma unroll
    for (int r = 0; r < 4; ++r) {
      size_t row = rowB + (size_t)qb * 64 + w * 16 + quad * 4 + r;
      size_t col = (size_t)h * 64 + j * 16 + l15;
      out[row * 2048 + col] = f2bf(oacc[j][r] / lrun[r]);
    }
}

extern "C" void kernel_launch(void* const* d_in, const int* in_sizes, int n_in, void* d_out,
                              int out_size, void* d_ws, size_t ws_size, hipStream_t stream) {
  const float* x = (const float*)d_in[0];
  const float* fcos = (const float*)d_in[1];
  const float* fsin = (const float*)d_in[2];
  const float* wq = (const float*)d_in[3];
  const float* wk = (const float*)d_in[4];
  const float* wv = (const float*)d_in[5];
  const float* wo = (const float*)d_in[6];

  char* ws = (char*)d_ws;
  unsigned short* xb = (unsigned short*)ws;                          // 4096x2048 bf16 : 16 MiB
  unsigned short* wt = (unsigned short*)(ws + 16777216ull);          // 3072x2048 bf16 (wq^T|wk^T|wv^T)
  unsigned short* wot = (unsigned short*)(ws + 29360128ull);         // 2048x2048 bf16
  unsigned short* qkv = (unsigned short*)(ws + 37748736ull);         // 4096x3072 bf16
  unsigned short* attno = (unsigned short*)(ws + 62914560ull);       // 4096x2048 bf16
  unsigned short* vt = xb;  // reuse xb region after QKV GEMM consumed it (4 MiB needed)

  cast_f32_bf16<<<8192, 256, 0, stream>>>(x, xb, 2097152);
  transpose_cast<<<dim3(64, 64), dim3(32, 8), 0, stream>>>(wq, wt, 2048, 2048);
  transpose_cast<<<dim3(16, 64), dim3(32, 8), 0, stream>>>(wk, wt + 2048ull * 2048, 2048, 512);
  transpose_cast<<<dim3(16, 64), dim3(32, 8), 0, stream>>>(wv, wt + 2560ull * 2048, 2048, 512);
  transpose_cast<<<dim3(64, 64), dim3(32, 8), 0, stream>>>(wo, wot, 2048, 2048);

  // QKV: [4096 x 3072] = xb [4096x2048] @ [wq|wk|wv]
  gemm_bt<1><<<dim3(24, 32), 256, 0, stream>>>(xb, wt, qkv, 2048, 3072);
  rope_kernel<<<20480, 256, 0, stream>>>(qkv, fcos, fsin);
  // V^T into [b][kvh][d][s] (xb region is dead now)
  v_transpose<<<dim3(16, 128), dim3(32, 8), 0, stream>>>(qkv, vt);
  flash_attn<<<dim3(32, 32, 2), 256, 0, stream>>>(qkv, vt, attno);
  // out = attno @ wo  (fp32 out)
  gemm_bt<0><<<dim3(16, 32), 256, 0, stream>>>(attno, wot, d_out, 2048, 2048);
}

// Round 3
// 342.892 us; speedup vs baseline: 1.6318x; 1.4590x over previous
//
#include <hip/hip_runtime.h>
#include <hip/hip_bf16.h>

typedef __attribute__((ext_vector_type(8))) short short8;
typedef __attribute__((ext_vector_type(4))) float f32x4;

__device__ __forceinline__ unsigned short f2bf(float f) {
  union { float f; unsigned u; } v; v.f = f;
  unsigned r = v.u + 0x7FFFu + ((v.u >> 16) & 1u);
  return (unsigned short)(r >> 16);
}
__device__ __forceinline__ float bf2f(unsigned short h) {
  union { unsigned u; float f; } v; v.u = ((unsigned)h) << 16;
  return v.f;
}
__device__ __forceinline__ unsigned pkbf(float a, float b) {
  __hip_bfloat162 h = __float22bfloat162_rn(float2{a, b});
  union { __hip_bfloat162 h; unsigned u; } cv; cv.h = h;
  return cv.u;
}

// ---------------- cast fp32 -> bf16 (vectorized) ----------------
__global__ void cast_f32_bf16(const float* __restrict__ in, unsigned short* __restrict__ out, int n4) {
  int i = blockIdx.x * blockDim.x + threadIdx.x;
  if (i >= n4) return;
  float4 v = ((const float4*)in)[i];
  ushort4 o;
  o.x = f2bf(v.x); o.y = f2bf(v.y); o.z = f2bf(v.z); o.w = f2bf(v.w);
  ((ushort4*)out)[i] = o;
}

// ---------------- transpose + cast: in (K x N) fp32 -> out (N x K) bf16 ----------------
__global__ void transpose_cast(const float* __restrict__ in, unsigned short* __restrict__ out, int K, int N) {
  __shared__ float tile[32][33];
  int n0 = blockIdx.x * 32, k0 = blockIdx.y * 32;
  int x = threadIdx.x, y = threadIdx.y;  // 32 x 8
#pragma unroll
  for (int j = 0; j < 4; ++j) tile[y + 8 * j][x] = in[(size_t)(k0 + y + 8 * j) * N + n0 + x];
  __syncthreads();
#pragma unroll
  for (int j = 0; j < 4; ++j) out[(size_t)(n0 + y + 8 * j) * K + k0 + x] = f2bf(tile[x][y + 8 * j]);
}

// ---------------- V transpose: qkv V-slice [4096 x 512] -> vt [b][kvh][d][s] ----------------
__global__ void v_transpose(const unsigned short* __restrict__ qkv, unsigned short* __restrict__ vt) {
  __shared__ unsigned short tile[32][33];
  int c0 = blockIdx.x * 32, r0 = blockIdx.y * 32;
  int x = threadIdx.x, y = threadIdx.y;  // 32 x 8
#pragma unroll
  for (int j = 0; j < 4; ++j)
    tile[y + 8 * j][x] = qkv[(size_t)(r0 + y + 8 * j) * 3072 + 2560 + c0 + x];
  __syncthreads();
  int b = r0 >> 11;
  int kvh = c0 >> 6;
#pragma unroll
  for (int j = 0; j < 4; ++j) {
    int c = c0 + y + 8 * j, r = r0 + x;
    vt[((size_t)(b * 8 + kvh) * 64 + (c & 63)) * 2048 + (r & 2047)] = tile[x][y + 8 * j];
  }
}

// ---------------- GEMM: C(MxN) = A(MxK,bf16) * Bt(NxK,bf16)^T ; m97 structure ----------------
template <int OUT_BF16>
__global__ __launch_bounds__(256, 2) void gemm_bt(const unsigned short* __restrict__ A,
                                                  const unsigned short* __restrict__ Bt,
                                                  void* __restrict__ Cv, int K, int ldc) {
  __shared__ alignas(16) unsigned short As[128 * 32];
  __shared__ alignas(16) unsigned short Bs[128 * 32];
  const int t = threadIdx.x;
  const int lane = t & 63, w = t >> 6;
  const int l15 = lane & 15, quad = lane >> 4;
  const int bn0 = blockIdx.x * 128, bm0 = blockIdx.y * 128;
  const int wm = (w >> 1) * 64, wn = (w & 1) * 64;
  const unsigned short* Ab = A + (size_t)bm0 * K;
  const unsigned short* Bb = Bt + (size_t)bn0 * K;

  f32x4 acc[4][4];
  const f32x4 zf = {0.f, 0.f, 0.f, 0.f};
#pragma unroll
  for (int i = 0; i < 4; ++i)
#pragma unroll
    for (int j = 0; j < 4; ++j) acc[i][j] = zf;

  for (int k0 = 0; k0 < K; k0 += 32) {
    __syncthreads();
#pragma unroll
    for (int r = 0; r < 2; ++r) {
      int e = r * 256 + t;
      const unsigned short* ga = Ab + (size_t)(e >> 2) * K + k0 + (e & 3) * 8;
      __builtin_amdgcn_global_load_lds((const __attribute__((address_space(1))) void*)ga,
                                       (__attribute__((address_space(3))) void*)(As + e * 8), 16, 0, 0);
      const unsigned short* gb = Bb + (size_t)(e >> 2) * K + k0 + (e & 3) * 8;
      __builtin_amdgcn_global_load_lds((const __attribute__((address_space(1))) void*)gb,
                                       (__attribute__((address_space(3))) void*)(Bs + e * 8), 16, 0, 0);
    }
    __syncthreads();
    short8 af[4], bf[4];
#pragma unroll
    for (int i = 0; i < 4; ++i)
      af[i] = *reinterpret_cast<const short8*>(As + (wm + i * 16 + l15) * 32 + quad * 8);
#pragma unroll
    for (int j = 0; j < 4; ++j)
      bf[j] = *reinterpret_cast<const short8*>(Bs + (wn + j * 16 + l15) * 32 + quad * 8);
#pragma unroll
    for (int i = 0; i < 4; ++i)
#pragma unroll
      for (int j = 0; j < 4; ++j)
        acc[i][j] = __builtin_amdgcn_mfma_f32_16x16x32_bf16(af[i], bf[j], acc[i][j], 0, 0, 0);
  }
#pragma unroll
  for (int i = 0; i < 4; ++i)
#pragma unroll
    for (int j = 0; j < 4; ++j)
#pragma unroll
      for (int r = 0; r < 4; ++r) {
        size_t row = (size_t)(bm0 + wm + i * 16 + quad * 4 + r);
        size_t col = (size_t)(bn0 + wn + j * 16 + l15);
        if (OUT_BF16)
          ((unsigned short*)Cv)[row * ldc + col] = f2bf(acc[i][j][r]);
        else
          ((float*)Cv)[row * ldc + col] = acc[i][j][r];
      }
}

// ---------------- RoPE in-place on K columns only (Q is fused into flash) ----------------
__global__ void rope_k(unsigned short* __restrict__ qkv, const float* __restrict__ fcos,
                       const float* __restrict__ fsin) {
  int tid = blockIdx.x * 256 + threadIdx.x;  // 4096 rows x 256 pairs
  int row = tid >> 8, p = tid & 255;
  int col = 2048 + 2 * p;
  int s = row & 2047;
  int fi = p & 31;
  float c = fcos[s * 32 + fi], sn = fsin[s * 32 + fi];
  unsigned int* ptr = (unsigned int*)(qkv + (size_t)row * 3072 + col);
  unsigned int pr = *ptr;
  float xr = bf2f((unsigned short)(pr & 0xFFFFu));
  float xi = bf2f((unsigned short)(pr >> 16));
  float orr = xr * c - xi * sn;
  float oi = xr * sn + xi * c;
  *ptr = ((unsigned)f2bf(oi) << 16) | (unsigned)f2bf(orr);
}

// ---------------- flash attention: 128 q-rows/block, 4 waves x 32 rows ----------------
// S^T = K Q^T (operand-swapped MFMA) so P spills as packed b64 and reloads in A-layout.
// No-max softmax (bounded scores), deferred l-sum. V pre-transposed: vt [b][kvh][d][s].
__global__ __launch_bounds__(256, 4) void flash_attn(const unsigned short* __restrict__ qkv,
                                                     const unsigned short* __restrict__ vt,
                                                     const float* __restrict__ fcos,
                                                     const float* __restrict__ fsin,
                                                     unsigned short* __restrict__ out) {
  __shared__ alignas(16) unsigned short Ks[64 * 72];   // [kv][d]
  __shared__ alignas(16) unsigned short Vs[64 * 72];   // [d][kv]
  __shared__ alignas(16) unsigned short Ps[128 * 72];  // [q][kv], per-wave 32-row regions
  __shared__ float Ls[128];
  const int t = threadIdx.x, lane = t & 63, w = t >> 6;
  const int l15 = lane & 15, quad = lane >> 4;
  const int h = blockIdx.y, b = blockIdx.z;
  // decorrelate causal length across co-resident blocks (bijective per (h,b))
  const int qb = ((int)blockIdx.x ^ ((h >> 2) & 15) ^ ((b & 1) << 3)) & 15;
  const int q0 = qb * 128;
  const int kvh = h >> 2;
  const size_t rowB = (size_t)b * 2048;
  const unsigned short* Qg = qkv + (rowB + q0) * 3072 + h * 64;
  const unsigned short* Kg = qkv + rowB * 3072 + 2048 + kvh * 64;
  const unsigned short* Vtg = vt + (size_t)(b * 8 + kvh) * 64 * 2048;
  const float SC = 0.18033688011112042f;  // (1/8) * log2(e)

  // ---- Q fragments with fused RoPE (pairs are in-lane: cols quad*8..quad*8+7) ----
  short8 qf[2][2];
#pragma unroll
  for (int mt = 0; mt < 2; ++mt)
#pragma unroll
    for (int s = 0; s < 2; ++s) {
      int qrow = w * 32 + mt * 16 + l15;
      short8 raw = *reinterpret_cast<const short8*>(Qg + (size_t)qrow * 3072 + s * 32 + quad * 8);
      f32x4 c4 = *reinterpret_cast<const f32x4*>(fcos + (size_t)(q0 + qrow) * 32 + s * 16 + quad * 4);
      f32x4 s4 = *reinterpret_cast<const f32x4*>(fsin + (size_t)(q0 + qrow) * 32 + s * 16 + quad * 4);
      short8 o;
#pragma unroll
      for (int k = 0; k < 4; ++k) {
        float xr = bf2f((unsigned short)raw[2 * k]);
        float xi = bf2f((unsigned short)raw[2 * k + 1]);
        o[2 * k] = (short)f2bf(xr * c4[k] - xi * s4[k]);
        o[2 * k + 1] = (short)f2bf(xr * s4[k] + xi * c4[k]);
      }
      qf[mt][s] = o;
    }

  const f32x4 zf = {0.f, 0.f, 0.f, 0.f};
  f32x4 oacc[2][4];
#pragma unroll
  for (int mt = 0; mt < 2; ++mt)
#pragma unroll
    for (int nt = 0; nt < 4; ++nt) oacc[mt][nt] = zf;
  float lsum[2] = {0.f, 0.f};

  const int kb_end = 2 * qb + 2;
  const int srow = t >> 3, sc8 = (t & 7) * 8;  // staging coords (this thread covers rows srow, srow+32)
  short8 kreg[2], vreg[2];
#pragma unroll
  for (int r = 0; r < 2; ++r) {
    kreg[r] = *reinterpret_cast<const short8*>(Kg + (size_t)(srow + 32 * r) * 3072 + sc8);
    vreg[r] = *reinterpret_cast<const short8*>(Vtg + (size_t)(srow + 32 * r) * 2048 + sc8);
  }

  for (int kb = 0; kb < kb_end; ++kb) {
    __syncthreads();
#pragma unroll
    for (int r = 0; r < 2; ++r) {
      *reinterpret_cast<short8*>(Ks + (srow + 32 * r) * 72 + sc8) = kreg[r];
      *reinterpret_cast<short8*>(Vs + (srow + 32 * r) * 72 + sc8) = vreg[r];
    }
    __syncthreads();
    if (kb + 1 < kb_end) {  // prefetch next tile into regs; consumed after next barrier
#pragma unroll
      for (int r = 0; r < 2; ++r) {
        kreg[r] = *reinterpret_cast<const short8*>(Kg + (size_t)((kb + 1) * 64 + srow + 32 * r) * 3072 + sc8);
        vreg[r] = *reinterpret_cast<const short8*>(Vtg + (size_t)(srow + 32 * r) * 2048 + (kb + 1) * 64 + sc8);
      }
    }
    const int qmaxw = q0 + w * 32 + 31;
    if (kb * 64 > qmaxw) continue;  // whole wave fully masked for this tile
    const bool needMask = (kb * 64 + 63) > (q0 + w * 32);

    // S^T per kv-tile, then exp + packed spill (st regs reused per kvt)
#pragma unroll
    for (int kvt = 0; kvt < 4; ++kvt) {
      f32x4 st0 = zf, st1 = zf;
#pragma unroll
      for (int s = 0; s < 2; ++s) {
        short8 kf = *reinterpret_cast<const short8*>(Ks + (kvt * 16 + l15) * 72 + s * 32 + quad * 8);
        st0 = __builtin_amdgcn_mfma_f32_16x16x32_bf16(kf, qf[0][s], st0, 0, 0, 0);
        st1 = __builtin_amdgcn_mfma_f32_16x16x32_bf16(kf, qf[1][s], st1, 0, 0, 0);
      }
      const int kvb = kb * 64 + kvt * 16 + quad * 4;
#pragma unroll
      for (int qt = 0; qt < 2; ++qt) {
        const f32x4 stv = qt ? st1 : st0;
        const int qg = q0 + w * 32 + qt * 16 + l15;
        float p[4];
#pragma unroll
        for (int r = 0; r < 4; ++r) {
          float pv = exp2f(stv[r] * SC);
          p[r] = (needMask && (kvb + r > qg)) ? 0.f : pv;
        }
        lsum[qt] += (p[0] + p[1]) + (p[2] + p[3]);
        *reinterpret_cast<uint2*>(Ps + (size_t)(w * 32 + qt * 16 + l15) * 72 + kvt * 16 + quad * 4) =
            make_uint2(pkbf(p[0], p[1]), pkbf(p[2], p[3]));
      }
    }

    // O += P V  (A = P rows from own wave's Ps region, B = V from Vs[d][kv])
#pragma unroll
    for (int s = 0; s < 2; ++s) {
      short8 vf[4];
#pragma unroll
      for (int nt = 0; nt < 4; ++nt)
        vf[nt] = *reinterpret_cast<const short8*>(Vs + (nt * 16 + l15) * 72 + s * 32 + quad * 8);
#pragma unroll
      for (int mt = 0; mt < 2; ++mt) {
        short8 pf = *reinterpret_cast<const short8*>(Ps + (size_t)(w * 32 + mt * 16 + l15) * 72 + s * 32 + quad * 8);
#pragma unroll
        for (int nt = 0; nt < 4; ++nt)
          oacc[mt][nt] = __builtin_amdgcn_mfma_f32_16x16x32_bf16(pf, vf[nt], oacc[mt][nt], 0, 0, 0);
      }
    }
  }

  // ---- epilogue: finish l-sums (reduce over quads), broadcast via LDS, scale & store ----
#pragma unroll
  for (int qt = 0; qt < 2; ++qt) {
    lsum[qt] += __shfl_xor(lsum[qt], 16, 64);
    lsum[qt] += __shfl_xor(lsum[qt], 32, 64);
  }
  if (quad == 0) {
    Ls[w * 32 + l15] = lsum[0];
    Ls[w * 32 + 16 + l15] = lsum[1];
  }
  // within-wave LDS RAW; compiler orders via lgkmcnt
  float linv[2][4];
#pragma unroll
  for (int mt = 0; mt < 2; ++mt)
#pragma unroll
    for (int r = 0; r < 4; ++r) linv[mt][r] = 1.f / Ls[w * 32 + mt * 16 + quad * 4 + r];

#pragma unroll
  for (int mt = 0; mt < 2; ++mt)
#pragma unroll
    for (int nt = 0; nt < 4; ++nt)
#pragma unroll
      for (int r = 0; r < 4; ++r) {
        size_t row = rowB + (size_t)(q0 + w * 32 + mt * 16 + quad * 4 + r);
        size_t col = (size_t)h * 64 + nt * 16 + l15;
        out[row * 2048 + col] = f2bf(oacc[mt][nt][r] * linv[mt][r]);
      }
}

extern "C" void kernel_launch(void* const* d_in, const int* in_sizes, int n_in, void* d_out,
                              int out_size, void* d_ws, size_t ws_size, hipStream_t stream) {
  const float* x = (const float*)d_in[0];
  const float* fcos = (const float*)d_in[1];
  const float* fsin = (const float*)d_in[2];
  const float* wq = (const float*)d_in[3];
  const float* wk = (const float*)d_in[4];
  const float* wv = (const float*)d_in[5];
  const float* wo = (const float*)d_in[6];

  char* ws = (char*)d_ws;
  unsigned short* xb = (unsigned short*)ws;                          // 4096x2048 bf16
  unsigned short* wt = (unsigned short*)(ws + 16777216ull);          // 3072x2048 bf16
  unsigned short* wot = (unsigned short*)(ws + 29360128ull);         // 2048x2048 bf16
  unsigned short* qkv = (unsigned short*)(ws + 37748736ull);         // 4096x3072 bf16
  unsigned short* attno = (unsigned short*)(ws + 62914560ull);       // 4096x2048 bf16
  unsigned short* vt = xb;  // xb dead after QKV GEMM

  cast_f32_bf16<<<8192, 256, 0, stream>>>(x, xb, 2097152);
  transpose_cast<<<dim3(64, 64), dim3(32, 8), 0, stream>>>(wq, wt, 2048, 2048);
  transpose_cast<<<dim3(16, 64), dim3(32, 8), 0, stream>>>(wk, wt + 2048ull * 2048, 2048, 512);
  transpose_cast<<<dim3(16, 64), dim3(32, 8), 0, stream>>>(wv, wt + 2560ull * 2048, 2048, 512);
  transpose_cast<<<dim3(64, 64), dim3(32, 8), 0, stream>>>(wo, wot, 2048, 2048);

  gemm_bt<1><<<dim3(24, 32), 256, 0, stream>>>(xb, wt, qkv, 2048, 3072);
  rope_k<<<4096, 256, 0, stream>>>(qkv, fcos, fsin);
  v_transpose<<<dim3(16, 128), dim3(32, 8), 0, stream>>>(qkv, vt);
  flash_attn<<<dim3(16, 32, 2), 256, 0, stream>>>(qkv, vt, fcos, fsin, attno);
  gemm_bt<0><<<dim3(16, 32), 256, 0, stream>>>(attno, wot, d_out, 2048, 2048);
}

// Round 4
// 297.872 us; speedup vs baseline: 1.8784x; 1.1511x over previous
//
#include <hip/hip_runtime.h>
#include <hip/hip_bf16.h>

typedef __attribute__((ext_vector_type(8))) short short8;
typedef __attribute__((ext_vector_type(4))) float f32x4;

__device__ __forceinline__ unsigned short f2bf(float f) {
  union { float f; unsigned u; } v; v.f = f;
  unsigned r = v.u + 0x7FFFu + ((v.u >> 16) & 1u);
  return (unsigned short)(r >> 16);
}
__device__ __forceinline__ float bf2f(unsigned short h) {
  union { unsigned u; float f; } v; v.u = ((unsigned)h) << 16;
  return v.f;
}
__device__ __forceinline__ unsigned pkbf(float a, float b) {
  __hip_bfloat162 h = __float22bfloat162_rn(float2{a, b});
  union { __hip_bfloat162 h; unsigned u; } cv; cv.h = h;
  return cv.u;
}

// ---------------- cast fp32 -> bf16 (vectorized) ----------------
__global__ void cast_f32_bf16(const float* __restrict__ in, unsigned short* __restrict__ out, int n4) {
  int i = blockIdx.x * blockDim.x + threadIdx.x;
  if (i >= n4) return;
  float4 v = ((const float4*)in)[i];
  ushort4 o;
  o.x = f2bf(v.x); o.y = f2bf(v.y); o.z = f2bf(v.z); o.w = f2bf(v.w);
  ((ushort4*)out)[i] = o;
}

// ---------------- merged transpose+cast for all 4 weights (one launch) ----------------
__global__ void transpose_cast_all(const float* __restrict__ wq, const float* __restrict__ wk,
                                   const float* __restrict__ wv, const float* __restrict__ wo,
                                   unsigned short* __restrict__ wt, unsigned short* __restrict__ wot) {
  __shared__ float tile[32][33];
  const int z = blockIdx.z;
  const float* src;
  unsigned short* dst;
  int N;
  if (z == 0) { src = wq; dst = wt; N = 2048; }
  else if (z == 1) { src = wk; dst = wt + 2048ull * 2048; N = 512; }
  else if (z == 2) { src = wv; dst = wt + 2560ull * 2048; N = 512; }
  else { src = wo; dst = wot; N = 2048; }
  const int K = 2048;
  int n0 = blockIdx.x * 32, k0 = blockIdx.y * 32;
  if (n0 >= N) return;
  int x = threadIdx.x, y = threadIdx.y;  // 32 x 8
#pragma unroll
  for (int j = 0; j < 4; ++j) tile[y + 8 * j][x] = src[(size_t)(k0 + y + 8 * j) * N + n0 + x];
  __syncthreads();
#pragma unroll
  for (int j = 0; j < 4; ++j) dst[(size_t)(n0 + y + 8 * j) * K + k0 + x] = f2bf(tile[x][y + 8 * j]);
}

// ---------------- V transpose: qkv V-slice [4096 x 512] -> vt [b][kvh][d][s] ----------------
__global__ void v_transpose(const unsigned short* __restrict__ qkv, unsigned short* __restrict__ vt) {
  __shared__ unsigned short tile[32][33];
  int c0 = blockIdx.x * 32, r0 = blockIdx.y * 32;
  int x = threadIdx.x, y = threadIdx.y;  // 32 x 8
#pragma unroll
  for (int j = 0; j < 4; ++j)
    tile[y + 8 * j][x] = qkv[(size_t)(r0 + y + 8 * j) * 3072 + 2560 + c0 + x];
  __syncthreads();
  int b = r0 >> 11;
  int kvh = c0 >> 6;
#pragma unroll
  for (int j = 0; j < 4; ++j) {
    int c = c0 + y + 8 * j, r = r0 + x;
    vt[((size_t)(b * 8 + kvh) * 64 + (c & 63)) * 2048 + (r & 2047)] = tile[x][y + 8 * j];
  }
}

// ---------------- GEMM: C(MxN) = A(MxK,bf16) * Bt(NxK,bf16)^T ; m97 structure ----------------
template <int OUT_BF16>
__global__ __launch_bounds__(256, 2) void gemm_bt(const unsigned short* __restrict__ A,
                                                  const unsigned short* __restrict__ Bt,
                                                  void* __restrict__ Cv, int K, int ldc) {
  __shared__ alignas(16) unsigned short As[128 * 32];
  __shared__ alignas(16) unsigned short Bs[128 * 32];
  const int t = threadIdx.x;
  const int lane = t & 63, w = t >> 6;
  const int l15 = lane & 15, quad = lane >> 4;
  const int bn0 = blockIdx.x * 128, bm0 = blockIdx.y * 128;
  const int wm = (w >> 1) * 64, wn = (w & 1) * 64;
  const unsigned short* Ab = A + (size_t)bm0 * K;
  const unsigned short* Bb = Bt + (size_t)bn0 * K;

  f32x4 acc[4][4];
  const f32x4 zf = {0.f, 0.f, 0.f, 0.f};
#pragma unroll
  for (int i = 0; i < 4; ++i)
#pragma unroll
    for (int j = 0; j < 4; ++j) acc[i][j] = zf;

  for (int k0 = 0; k0 < K; k0 += 32) {
    __syncthreads();
#pragma unroll
    for (int r = 0; r < 2; ++r) {
      int e = r * 256 + t;
      const unsigned short* ga = Ab + (size_t)(e >> 2) * K + k0 + (e & 3) * 8;
      __builtin_amdgcn_global_load_lds((const __attribute__((address_space(1))) void*)ga,
                                       (__attribute__((address_space(3))) void*)(As + e * 8), 16, 0, 0);
      const unsigned short* gb = Bb + (size_t)(e >> 2) * K + k0 + (e & 3) * 8;
      __builtin_amdgcn_global_load_lds((const __attribute__((address_space(1))) void*)gb,
                                       (__attribute__((address_space(3))) void*)(Bs + e * 8), 16, 0, 0);
    }
    __syncthreads();
    short8 af[4], bf[4];
#pragma unroll
    for (int i = 0; i < 4; ++i)
      af[i] = *reinterpret_cast<const short8*>(As + (wm + i * 16 + l15) * 32 + quad * 8);
#pragma unroll
    for (int j = 0; j < 4; ++j)
      bf[j] = *reinterpret_cast<const short8*>(Bs + (wn + j * 16 + l15) * 32 + quad * 8);
#pragma unroll
    for (int i = 0; i < 4; ++i)
#pragma unroll
      for (int j = 0; j < 4; ++j)
        acc[i][j] = __builtin_amdgcn_mfma_f32_16x16x32_bf16(af[i], bf[j], acc[i][j], 0, 0, 0);
  }
#pragma unroll
  for (int i = 0; i < 4; ++i)
#pragma unroll
    for (int j = 0; j < 4; ++j)
#pragma unroll
      for (int r = 0; r < 4; ++r) {
        size_t row = (size_t)(bm0 + wm + i * 16 + quad * 4 + r);
        size_t col = (size_t)(bn0 + wn + j * 16 + l15);
        if (OUT_BF16)
          ((unsigned short*)Cv)[row * ldc + col] = f2bf(acc[i][j][r]);
        else
          ((float*)Cv)[row * ldc + col] = acc[i][j][r];
      }
}

// ---------------- RoPE in-place on K columns only (Q is fused into flash) ----------------
__global__ void rope_k(unsigned short* __restrict__ qkv, const float* __restrict__ fcos,
                       const float* __restrict__ fsin) {
  int tid = blockIdx.x * 256 + threadIdx.x;  // 4096 rows x 256 pairs
  int row = tid >> 8, p = tid & 255;
  int col = 2048 + 2 * p;
  int s = row & 2047;
  int fi = p & 31;
  float c = fcos[s * 32 + fi], sn = fsin[s * 32 + fi];
  unsigned int* ptr = (unsigned int*)(qkv + (size_t)row * 3072 + col);
  unsigned int pr = *ptr;
  float xr = bf2f((unsigned short)(pr & 0xFFFFu));
  float xi = bf2f((unsigned short)(pr >> 16));
  float orr = xr * c - xi * sn;
  float oi = xr * sn + xi * c;
  *ptr = ((unsigned)f2bf(oi) << 16) | (unsigned)f2bf(orr);
}

// ---------------- flash attention: 128 q-rows/block, 4 waves x 32 rows ----------------
// S^T = K Q^T; softmax scale folded into Q; XOR-swizzled stride-64 LDS (conflict-free);
// CU-balanced causal lengths via qb = x ^ 15*(h>>4). V pre-transposed: vt [b][kvh][d][s].
__global__ __launch_bounds__(256, 4) void flash_attn(const unsigned short* __restrict__ qkv,
                                                     const unsigned short* __restrict__ vt,
                                                     const float* __restrict__ fcos,
                                                     const float* __restrict__ fsin,
                                                     unsigned short* __restrict__ out) {
  __shared__ alignas(16) unsigned short Ks[64 * 64];   // [kv][d], swizzled chunks
  __shared__ alignas(16) unsigned short Vs[64 * 64];   // [d][kv], swizzled
  __shared__ alignas(16) unsigned short Ps[128 * 64];  // [q][kv], swizzled, per-wave regions
  __shared__ float Ls[128];
  const int t = threadIdx.x, lane = t & 63, w = t >> 6;
  const int l15 = lane & 15, quad = lane >> 4;
  const int h = blockIdx.y, b = blockIdx.z;
  // co-resident blocks (idx +256 => h+16) pair qb with 15-qb: every CU gets 68 tile-units
  const int qb = ((int)blockIdx.x ^ (15 * (h >> 4))) & 15;
  const int q0 = qb * 128;
  const int kvh = h >> 2;
  const size_t rowB = (size_t)b * 2048;
  const unsigned short* Qg = qkv + (rowB + q0) * 3072 + h * 64;
  const unsigned short* Kg = qkv + rowB * 3072 + 2048 + kvh * 64;
  const unsigned short* Vtg = vt + (size_t)(b * 8 + kvh) * 64 * 2048;
  const float SC = 0.18033688011112042f;  // (1/8) * log2(e) — folded into Q

  // ---- Q fragments: fused RoPE, softmax scale folded ----
  short8 qf[2][2];
#pragma unroll
  for (int mt = 0; mt < 2; ++mt)
#pragma unroll
    for (int s = 0; s < 2; ++s) {
      int qrow = w * 32 + mt * 16 + l15;
      short8 raw = *reinterpret_cast<const short8*>(Qg + (size_t)qrow * 3072 + s * 32 + quad * 8);
      f32x4 c4 = *reinterpret_cast<const f32x4*>(fcos + (size_t)(q0 + qrow) * 32 + s * 16 + quad * 4);
      f32x4 s4 = *reinterpret_cast<const f32x4*>(fsin + (size_t)(q0 + qrow) * 32 + s * 16 + quad * 4);
      short8 o;
#pragma unroll
      for (int k = 0; k < 4; ++k) {
        float xr = bf2f((unsigned short)raw[2 * k]);
        float xi = bf2f((unsigned short)raw[2 * k + 1]);
        o[2 * k] = (short)f2bf((xr * c4[k] - xi * s4[k]) * SC);
        o[2 * k + 1] = (short)f2bf((xr * s4[k] + xi * c4[k]) * SC);
      }
      qf[mt][s] = o;
    }

  const f32x4 zf = {0.f, 0.f, 0.f, 0.f};
  f32x4 oacc[2][4];
#pragma unroll
  for (int mt = 0; mt < 2; ++mt)
#pragma unroll
    for (int nt = 0; nt < 4; ++nt) oacc[mt][nt] = zf;
  float lsum[2] = {0.f, 0.f};

  const int kb_end = 2 * qb + 2;
  // staging coords: thread covers rows srow, srow+32 ; chunk sc8 of 8 shorts, XOR-swizzled
  const int srow = t >> 3, sc8 = t & 7;
  const int soff = srow * 64 + ((sc8 ^ (srow & 7)) * 8);
  const int asw = l15 & 7;  // swizzle key for all compute-side rows (row%8 == l15%8)
  short8 kreg[2], vreg[2];
#pragma unroll
  for (int r = 0; r < 2; ++r) {
    kreg[r] = *reinterpret_cast<const short8*>(Kg + (size_t)(srow + 32 * r) * 3072 + sc8 * 8);
    vreg[r] = *reinterpret_cast<const short8*>(Vtg + (size_t)(srow + 32 * r) * 2048 + sc8 * 8);
  }

  for (int kb = 0; kb < kb_end; ++kb) {
    __syncthreads();
#pragma unroll
    for (int r = 0; r < 2; ++r) {
      *reinterpret_cast<short8*>(Ks + soff + r * 32 * 64) = kreg[r];
      *reinterpret_cast<short8*>(Vs + soff + r * 32 * 64) = vreg[r];
    }
    __syncthreads();
    if (kb + 1 < kb_end) {
#pragma unroll
      for (int r = 0; r < 2; ++r) {
        kreg[r] = *reinterpret_cast<const short8*>(Kg + (size_t)((kb + 1) * 64 + srow + 32 * r) * 3072 + sc8 * 8);
        vreg[r] = *reinterpret_cast<const short8*>(Vtg + (size_t)(srow + 32 * r) * 2048 + (kb + 1) * 64 + sc8 * 8);
      }
    }
    const int qmaxw = q0 + w * 32 + 31;
    if (kb * 64 > qmaxw) continue;  // wave fully masked for this tile
    const bool needMask = (kb * 64 + 63) > (q0 + w * 32);

#pragma unroll
    for (int kvt = 0; kvt < 4; ++kvt) {
      f32x4 st0 = zf, st1 = zf;
#pragma unroll
      for (int s = 0; s < 2; ++s) {
        short8 kf = *reinterpret_cast<const short8*>(Ks + (kvt * 16 + l15) * 64 + ((s * 4 + quad) ^ asw) * 8);
        st0 = __builtin_amdgcn_mfma_f32_16x16x32_bf16(kf, qf[0][s], st0, 0, 0, 0);
        st1 = __builtin_amdgcn_mfma_f32_16x16x32_bf16(kf, qf[1][s], st1, 0, 0, 0);
      }
      const int pcol = ((kvt * 2 + (quad >> 1)) ^ asw) * 8 + (quad & 1) * 4;
      if (needMask) {
        const int kvb = kb * 64 + kvt * 16 + quad * 4;
#pragma unroll
        for (int qt = 0; qt < 2; ++qt) {
          const f32x4 stv = qt ? st1 : st0;
          const int qg = q0 + w * 32 + qt * 16 + l15;
          float p[4];
#pragma unroll
          for (int r = 0; r < 4; ++r) {
            float pv = __builtin_amdgcn_exp2f(stv[r]);
            p[r] = (kvb + r > qg) ? 0.f : pv;
          }
          lsum[qt] += (p[0] + p[1]) + (p[2] + p[3]);
          *reinterpret_cast<uint2*>(Ps + (size_t)(w * 32 + qt * 16 + l15) * 64 + pcol) =
              make_uint2(pkbf(p[0], p[1]), pkbf(p[2], p[3]));
        }
      } else {
#pragma unroll
        for (int qt = 0; qt < 2; ++qt) {
          const f32x4 stv = qt ? st1 : st0;
          float p[4];
#pragma unroll
          for (int r = 0; r < 4; ++r) p[r] = __builtin_amdgcn_exp2f(stv[r]);
          lsum[qt] += (p[0] + p[1]) + (p[2] + p[3]);
          *reinterpret_cast<uint2*>(Ps + (size_t)(w * 32 + qt * 16 + l15) * 64 + pcol) =
              make_uint2(pkbf(p[0], p[1]), pkbf(p[2], p[3]));
        }
      }
    }

    // O += P V
#pragma unroll
    for (int s = 0; s < 2; ++s) {
      short8 vf[4];
#pragma unroll
      for (int nt = 0; nt < 4; ++nt)
        vf[nt] = *reinterpret_cast<const short8*>(Vs + (nt * 16 + l15) * 64 + ((s * 4 + quad) ^ asw) * 8);
#pragma unroll
      for (int mt = 0; mt < 2; ++mt) {
        short8 pf = *reinterpret_cast<const short8*>(Ps + (size_t)(w * 32 + mt * 16 + l15) * 64 + ((s * 4 + quad) ^ asw) * 8);
#pragma unroll
        for (int nt = 0; nt < 4; ++nt)
          oacc[mt][nt] = __builtin_amdgcn_mfma_f32_16x16x32_bf16(pf, vf[nt], oacc[mt][nt], 0, 0, 0);
      }
    }
  }

  // ---- epilogue: finish l-sums, broadcast via LDS, scale & store ----
#pragma unroll
  for (int qt = 0; qt < 2; ++qt) {
    lsum[qt] += __shfl_xor(lsum[qt], 16, 64);
    lsum[qt] += __shfl_xor(lsum[qt], 32, 64);
  }
  if (quad == 0) {
    Ls[w * 32 + l15] = lsum[0];
    Ls[w * 32 + 16 + l15] = lsum[1];
  }
  float linv[2][4];
#pragma unroll
  for (int mt = 0; mt < 2; ++mt)
#pragma unroll
    for (int r = 0; r < 4; ++r) linv[mt][r] = 1.f / Ls[w * 32 + mt * 16 + quad * 4 + r];

#pragma unroll
  for (int mt = 0; mt < 2; ++mt)
#pragma unroll
    for (int nt = 0; nt < 4; ++nt)
#pragma unroll
      for (int r = 0; r < 4; ++r) {
        size_t row = rowB + (size_t)(q0 + w * 32 + mt * 16 + quad * 4 + r);
        size_t col = (size_t)h * 64 + nt * 16 + l15;
        out[row * 2048 + col] = f2bf(oacc[mt][nt][r] * linv[mt][r]);
      }
}

extern "C" void kernel_launch(void* const* d_in, const int* in_sizes, int n_in, void* d_out,
                              int out_size, void* d_ws, size_t ws_size, hipStream_t stream) {
  const float* x = (const float*)d_in[0];
  const float* fcos = (const float*)d_in[1];
  const float* fsin = (const float*)d_in[2];
  const float* wq = (const float*)d_in[3];
  const float* wk = (const float*)d_in[4];
  const float* wv = (const float*)d_in[5];
  const float* wo = (const float*)d_in[6];

  char* ws = (char*)d_ws;
  unsigned short* xb = (unsigned short*)ws;                          // 4096x2048 bf16
  unsigned short* wt = (unsigned short*)(ws + 16777216ull);          // 3072x2048 bf16
  unsigned short* wot = (unsigned short*)(ws + 29360128ull);         // 2048x2048 bf16
  unsigned short* qkv = (unsigned short*)(ws + 37748736ull);         // 4096x3072 bf16
  unsigned short* attno = (unsigned short*)(ws + 62914560ull);       // 4096x2048 bf16
  unsigned short* vt = xb;  // xb dead after QKV GEMM

  cast_f32_bf16<<<8192, 256, 0, stream>>>(x, xb, 2097152);
  transpose_cast_all<<<dim3(64, 64, 4), dim3(32, 8), 0, stream>>>(wq, wk, wv, wo, wt, wot);

  gemm_bt<1><<<dim3(24, 32), 256, 0, stream>>>(xb, wt, qkv, 2048, 3072);
  rope_k<<<4096, 256, 0, stream>>>(qkv, fcos, fsin);
  v_transpose<<<dim3(16, 128), dim3(32, 8), 0, stream>>>(qkv, vt);
  flash_attn<<<dim3(16, 32, 2), 256, 0, stream>>>(qkv, vt, fcos, fsin, attno);
  gemm_bt<0><<<dim3(16, 32), 256, 0, stream>>>(attno, wot, d_out, 2048, 2048);
}

// Round 5
// 272.027 us; speedup vs baseline: 2.0568x; 1.0950x over previous
//
#include <hip/hip_runtime.h>
#include <hip/hip_bf16.h>

typedef __attribute__((ext_vector_type(8))) short short8;
typedef __attribute__((ext_vector_type(4))) float f32x4;

__device__ __forceinline__ unsigned short f2bf(float f) {
  union { float f; unsigned u; } v; v.f = f;
  unsigned r = v.u + 0x7FFFu + ((v.u >> 16) & 1u);
  return (unsigned short)(r >> 16);
}
__device__ __forceinline__ float bf2f(unsigned short h) {
  union { unsigned u; float f; } v; v.u = ((unsigned)h) << 16;
  return v.f;
}
__device__ __forceinline__ unsigned pkbf(float a, float b) {
  __hip_bfloat162 h = __float22bfloat162_rn(float2{a, b});
  union { __hip_bfloat162 h; unsigned u; } cv; cv.h = h;
  return cv.u;
}

// ---------------- prep: cast x -> bf16 (z=0) + transpose+cast 4 weights (z=1..4) ----------------
__global__ void prep(const float* __restrict__ x, const float* __restrict__ wq,
                     const float* __restrict__ wk, const float* __restrict__ wv,
                     const float* __restrict__ wo, unsigned short* __restrict__ xb,
                     unsigned short* __restrict__ wt, unsigned short* __restrict__ wot) {
  const int z = blockIdx.z, tid = threadIdx.x;
  if (z == 0) {
    int id = blockIdx.y * 64 + blockIdx.x;  // 0..4095
#pragma unroll
    for (int rep = 0; rep < 2; ++rep) {
      int i = (rep * 4096 + id) * 256 + tid;  // 2M float4 total
      float4 v = ((const float4*)x)[i];
      ushort4 o;
      o.x = f2bf(v.x); o.y = f2bf(v.y); o.z = f2bf(v.z); o.w = f2bf(v.w);
      ((ushort4*)xb)[i] = o;
    }
    return;
  }
  __shared__ float tile[32][33];
  const float* src;
  unsigned short* dst;
  int N;
  if (z == 1) { src = wq; dst = wt; N = 2048; }
  else if (z == 2) { src = wk; dst = wt + 2048ull * 2048; N = 512; }
  else if (z == 3) { src = wv; dst = wt + 2560ull * 2048; N = 512; }
  else { src = wo; dst = wot; N = 2048; }
  const int K = 2048;
  int n0 = blockIdx.x * 32, k0 = blockIdx.y * 32;
  if (n0 >= N) return;
  int xx = tid & 31, yy = tid >> 5;  // 32 x 8
#pragma unroll
  for (int j = 0; j < 4; ++j) tile[yy + 8 * j][xx] = src[(size_t)(k0 + yy + 8 * j) * N + n0 + xx];
  __syncthreads();
#pragma unroll
  for (int j = 0; j < 4; ++j) dst[(size_t)(n0 + yy + 8 * j) * K + k0 + xx] = f2bf(tile[xx][yy + 8 * j]);
}

// ---------------- GEMM BK=64, swizzled LDS: C(MxN) = A(MxK) * Bt(NxK)^T ----------------
// MODE 0: fp32 C (ldc), vt unused. MODE 1: QKV epilogue — cols<2560 bf16 to C (ldc=2560),
// cols>=2560 (V) packed-b64 transposed into vt[b][kvh][d][s].
template <int MODE>
__global__ __launch_bounds__(256, 2) void gemm_bt64(const unsigned short* __restrict__ A,
                                                    const unsigned short* __restrict__ Bt,
                                                    void* __restrict__ Cv, int K, int ldc,
                                                    unsigned short* __restrict__ vt) {
  __shared__ alignas(16) unsigned short As[128 * 64];
  __shared__ alignas(16) unsigned short Bs[128 * 64];
  const int t = threadIdx.x;
  const int lane = t & 63, w = t >> 6;
  const int l15 = lane & 15, quad = lane >> 4;
  const int bn0 = blockIdx.x * 128, bm0 = blockIdx.y * 128;
  const int wm = (w >> 1) * 64, wn = (w & 1) * 64;
  const unsigned short* Ab = A + (size_t)bm0 * K;
  const unsigned short* Bb = Bt + (size_t)bn0 * K;
  const int asw = l15 & 7;  // fragment-read swizzle key (row%8 == l15%8)

  f32x4 acc[4][4];
  const f32x4 zf = {0.f, 0.f, 0.f, 0.f};
#pragma unroll
  for (int i = 0; i < 4; ++i)
#pragma unroll
    for (int j = 0; j < 4; ++j) acc[i][j] = zf;

  for (int k0 = 0; k0 < K; k0 += 64) {
    __syncthreads();
    // stage 128x64 A and B tiles; LDS dest lane-linear, global chunk XOR-swizzled so
    // LDS slot (row, c) holds global chunk c^(row&7)  => conflict-free b128 frag reads
#pragma unroll
    for (int r = 0; r < 4; ++r) {
      int e = r * 256 + t;
      int row = e >> 3, cslot = e & 7;
      int cg = cslot ^ (row & 7);
      const unsigned short* ga = Ab + (size_t)row * K + k0 + cg * 8;
      __builtin_amdgcn_global_load_lds((const __attribute__((address_space(1))) void*)ga,
                                       (__attribute__((address_space(3))) void*)(As + e * 8), 16, 0, 0);
      const unsigned short* gb = Bb + (size_t)row * K + k0 + cg * 8;
      __builtin_amdgcn_global_load_lds((const __attribute__((address_space(1))) void*)gb,
                                       (__attribute__((address_space(3))) void*)(Bs + e * 8), 16, 0, 0);
    }
    __syncthreads();
#pragma unroll
    for (int s = 0; s < 2; ++s) {
      short8 af[4], bf[4];
#pragma unroll
      for (int i = 0; i < 4; ++i)
        af[i] = *reinterpret_cast<const short8*>(As + (wm + i * 16 + l15) * 64 + (((s * 4 + quad) ^ asw) * 8));
#pragma unroll
      for (int j = 0; j < 4; ++j)
        bf[j] = *reinterpret_cast<const short8*>(Bs + (wn + j * 16 + l15) * 64 + (((s * 4 + quad) ^ asw) * 8));
#pragma unroll
      for (int i = 0; i < 4; ++i)
#pragma unroll
        for (int j = 0; j < 4; ++j)
          acc[i][j] = __builtin_amdgcn_mfma_f32_16x16x32_bf16(af[i], bf[j], acc[i][j], 0, 0, 0);
    }
  }

  if (MODE == 1 && bn0 >= 2560) {
    // V block -> vt[b][kvh][d][s], packed 4 rows (consecutive s) per b64 store
    const int b = bm0 >> 11;
#pragma unroll
    for (int i = 0; i < 4; ++i) {
      int srow = (bm0 + wm + i * 16 + quad * 4) & 2047;
#pragma unroll
      for (int j = 0; j < 4; ++j) {
        int vcol = bn0 - 2560 + wn + j * 16 + l15;
        int kvh = vcol >> 6, d = vcol & 63;
        uint2 pk = make_uint2(pkbf(acc[i][j][0], acc[i][j][1]), pkbf(acc[i][j][2], acc[i][j][3]));
        *reinterpret_cast<uint2*>(vt + ((size_t)(b * 8 + kvh) * 64 + d) * 2048 + srow) = pk;
      }
    }
  } else {
#pragma unroll
    for (int i = 0; i < 4; ++i)
#pragma unroll
      for (int j = 0; j < 4; ++j)
#pragma unroll
        for (int r = 0; r < 4; ++r) {
          size_t row = (size_t)(bm0 + wm + i * 16 + quad * 4 + r);
          size_t col = (size_t)(bn0 + wn + j * 16 + l15);
          if (MODE == 1)
            ((unsigned short*)Cv)[row * ldc + col] = f2bf(acc[i][j][r]);
          else
            ((float*)Cv)[row * ldc + col] = acc[i][j][r];
        }
  }
}

// ---------------- RoPE in-place on K columns (qkv stride 2560) ----------------
__global__ void rope_k(unsigned short* __restrict__ qkv, const float* __restrict__ fcos,
                       const float* __restrict__ fsin) {
  int tid = blockIdx.x * 256 + threadIdx.x;  // 4096 rows x 256 pairs
  int row = tid >> 8, p = tid & 255;
  int col = 2048 + 2 * p;
  int s = row & 2047;
  int fi = p & 31;
  float c = fcos[s * 32 + fi], sn = fsin[s * 32 + fi];
  unsigned int* ptr = (unsigned int*)(qkv + (size_t)row * 2560 + col);
  unsigned int pr = *ptr;
  float xr = bf2f((unsigned short)(pr & 0xFFFFu));
  float xi = bf2f((unsigned short)(pr >> 16));
  float orr = xr * c - xi * sn;
  float oi = xr * sn + xi * c;
  *ptr = ((unsigned)f2bf(oi) << 16) | (unsigned)f2bf(orr);
}

// ---------------- flash attention: 128 q-rows/block, 4 waves x 32 rows ----------------
__global__ __launch_bounds__(256, 4) void flash_attn(const unsigned short* __restrict__ qkv,
                                                     const unsigned short* __restrict__ vt,
                                                     const float* __restrict__ fcos,
                                                     const float* __restrict__ fsin,
                                                     unsigned short* __restrict__ out) {
  __shared__ alignas(16) unsigned short Ks[64 * 64];
  __shared__ alignas(16) unsigned short Vs[64 * 64];
  __shared__ alignas(16) unsigned short Ps[128 * 64];
  __shared__ float Ls[128];
  const int t = threadIdx.x, lane = t & 63, w = t >> 6;
  const int l15 = lane & 15, quad = lane >> 4;
  const int h = blockIdx.y, b = blockIdx.z;
  const int qb = ((int)blockIdx.x ^ (15 * (h >> 4))) & 15;
  const int q0 = qb * 128;
  const int kvh = h >> 2;
  const size_t rowB = (size_t)b * 2048;
  const unsigned short* Qg = qkv + (rowB + q0) * 2560 + h * 64;
  const unsigned short* Kg = qkv + rowB * 2560 + 2048 + kvh * 64;
  const unsigned short* Vtg = vt + (size_t)(b * 8 + kvh) * 64 * 2048;
  const float SC = 0.18033688011112042f;  // (1/8)*log2(e), folded into Q

  short8 qf[2][2];
#pragma unroll
  for (int mt = 0; mt < 2; ++mt)
#pragma unroll
    for (int s = 0; s < 2; ++s) {
      int qrow = w * 32 + mt * 16 + l15;
      short8 raw = *reinterpret_cast<const short8*>(Qg + (size_t)qrow * 2560 + s * 32 + quad * 8);
      f32x4 c4 = *reinterpret_cast<const f32x4*>(fcos + (size_t)(q0 + qrow) * 32 + s * 16 + quad * 4);
      f32x4 s4 = *reinterpret_cast<const f32x4*>(fsin + (size_t)(q0 + qrow) * 32 + s * 16 + quad * 4);
      short8 o;
#pragma unroll
      for (int k = 0; k < 4; ++k) {
        float xr = bf2f((unsigned short)raw[2 * k]);
        float xi = bf2f((unsigned short)raw[2 * k + 1]);
        o[2 * k] = (short)f2bf((xr * c4[k] - xi * s4[k]) * SC);
        o[2 * k + 1] = (short)f2bf((xr * s4[k] + xi * c4[k]) * SC);
      }
      qf[mt][s] = o;
    }

  const f32x4 zf = {0.f, 0.f, 0.f, 0.f};
  f32x4 oacc[2][4];
#pragma unroll
  for (int mt = 0; mt < 2; ++mt)
#pragma unroll
    for (int nt = 0; nt < 4; ++nt) oacc[mt][nt] = zf;
  float lsum[2] = {0.f, 0.f};

  const int kb_end = 2 * qb + 2;
  const int srow = t >> 3, sc8 = t & 7;
  const int soff = srow * 64 + ((sc8 ^ (srow & 7)) * 8);
  const int asw = l15 & 7;
  short8 kreg[2], vreg[2];
#pragma unroll
  for (int r = 0; r < 2; ++r) {
    kreg[r] = *reinterpret_cast<const short8*>(Kg + (size_t)(srow + 32 * r) * 2560 + sc8 * 8);
    vreg[r] = *reinterpret_cast<const short8*>(Vtg + (size_t)(srow + 32 * r) * 2048 + sc8 * 8);
  }

  for (int kb = 0; kb < kb_end; ++kb) {
    __syncthreads();
#pragma unroll
    for (int r = 0; r < 2; ++r) {
      *reinterpret_cast<short8*>(Ks + soff + r * 32 * 64) = kreg[r];
      *reinterpret_cast<short8*>(Vs + soff + r * 32 * 64) = vreg[r];
    }
    __syncthreads();
    if (kb + 1 < kb_end) {
#pragma unroll
      for (int r = 0; r < 2; ++r) {
        kreg[r] = *reinterpret_cast<const short8*>(Kg + (size_t)((kb + 1) * 64 + srow + 32 * r) * 2560 + sc8 * 8);
        vreg[r] = *reinterpret_cast<const short8*>(Vtg + (size_t)(srow + 32 * r) * 2048 + (kb + 1) * 64 + sc8 * 8);
      }
    }
    const int qmaxw = q0 + w * 32 + 31;
    if (kb * 64 > qmaxw) continue;
    const bool needMask = (kb * 64 + 63) > (q0 + w * 32);

#pragma unroll
    for (int kvt = 0; kvt < 4; ++kvt) {
      f32x4 st0 = zf, st1 = zf;
#pragma unroll
      for (int s = 0; s < 2; ++s) {
        short8 kf = *reinterpret_cast<const short8*>(Ks + (kvt * 16 + l15) * 64 + ((s * 4 + quad) ^ asw) * 8);
        st0 = __builtin_amdgcn_mfma_f32_16x16x32_bf16(kf, qf[0][s], st0, 0, 0, 0);
        st1 = __builtin_amdgcn_mfma_f32_16x16x32_bf16(kf, qf[1][s], st1, 0, 0, 0);
      }
      const int pcol = ((kvt * 2 + (quad >> 1)) ^ asw) * 8 + (quad & 1) * 4;
      if (needMask) {
        const int kvb = kb * 64 + kvt * 16 + quad * 4;
#pragma unroll
        for (int qt = 0; qt < 2; ++qt) {
          const f32x4 stv = qt ? st1 : st0;
          const int qg = q0 + w * 32 + qt * 16 + l15;
          float p[4];
#pragma unroll
          for (int r = 0; r < 4; ++r) {
            float pv = __builtin_amdgcn_exp2f(stv[r]);
            p[r] = (kvb + r > qg) ? 0.f : pv;
          }
          lsum[qt] += (p[0] + p[1]) + (p[2] + p[3]);
          *reinterpret_cast<uint2*>(Ps + (size_t)(w * 32 + qt * 16 + l15) * 64 + pcol) =
              make_uint2(pkbf(p[0], p[1]), pkbf(p[2], p[3]));
        }
      } else {
#pragma unroll
        for (int qt = 0; qt < 2; ++qt) {
          const f32x4 stv = qt ? st1 : st0;
          float p[4];
#pragma unroll
          for (int r = 0; r < 4; ++r) p[r] = __builtin_amdgcn_exp2f(stv[r]);
          lsum[qt] += (p[0] + p[1]) + (p[2] + p[3]);
          *reinterpret_cast<uint2*>(Ps + (size_t)(w * 32 + qt * 16 + l15) * 64 + pcol) =
              make_uint2(pkbf(p[0], p[1]), pkbf(p[2], p[3]));
        }
      }
    }

#pragma unroll
    for (int s = 0; s < 2; ++s) {
      short8 vf[4];
#pragma unroll
      for (int nt = 0; nt < 4; ++nt)
        vf[nt] = *reinterpret_cast<const short8*>(Vs + (nt * 16 + l15) * 64 + ((s * 4 + quad) ^ asw) * 8);
#pragma unroll
      for (int mt = 0; mt < 2; ++mt) {
        short8 pf = *reinterpret_cast<const short8*>(Ps + (size_t)(w * 32 + mt * 16 + l15) * 64 + ((s * 4 + quad) ^ asw) * 8);
#pragma unroll
        for (int nt = 0; nt < 4; ++nt)
          oacc[mt][nt] = __builtin_amdgcn_mfma_f32_16x16x32_bf16(pf, vf[nt], oacc[mt][nt], 0, 0, 0);
      }
    }
  }

#pragma unroll
  for (int qt = 0; qt < 2; ++qt) {
    lsum[qt] += __shfl_xor(lsum[qt], 16, 64);
    lsum[qt] += __shfl_xor(lsum[qt], 32, 64);
  }
  if (quad == 0) {
    Ls[w * 32 + l15] = lsum[0];
    Ls[w * 32 + 16 + l15] = lsum[1];
  }
  float linv[2][4];
#pragma unroll
  for (int mt = 0; mt < 2; ++mt)
#pragma unroll
    for (int r = 0; r < 4; ++r) linv[mt][r] = 1.f / Ls[w * 32 + mt * 16 + quad * 4 + r];

#pragma unroll
  for (int mt = 0; mt < 2; ++mt)
#pragma unroll
    for (int nt = 0; nt < 4; ++nt)
#pragma unroll
      for (int r = 0; r < 4; ++r) {
        size_t row = rowB + (size_t)(q0 + w * 32 + mt * 16 + quad * 4 + r);
        size_t col = (size_t)h * 64 + nt * 16 + l15;
        out[row * 2048 + col] = f2bf(oacc[mt][nt][r] * linv[mt][r]);
      }
}

extern "C" void kernel_launch(void* const* d_in, const int* in_sizes, int n_in, void* d_out,
                              int out_size, void* d_ws, size_t ws_size, hipStream_t stream) {
  const float* x = (const float*)d_in[0];
  const float* fcos = (const float*)d_in[1];
  const float* fsin = (const float*)d_in[2];
  const float* wq = (const float*)d_in[3];
  const float* wk = (const float*)d_in[4];
  const float* wv = (const float*)d_in[5];
  const float* wo = (const float*)d_in[6];

  char* ws = (char*)d_ws;
  unsigned short* xb = (unsigned short*)ws;                       // 4096x2048 bf16  @0      (16 MiB)
  unsigned short* wt = (unsigned short*)(ws + 16777216ull);       // 3072x2048 bf16  @16 MiB (12 MiB)
  unsigned short* wot = (unsigned short*)(ws + 29360128ull);      // 2048x2048 bf16  @28 MiB (8 MiB)
  unsigned short* qkv = (unsigned short*)(ws + 37748736ull);      // 4096x2560 bf16  @36 MiB (20 MiB)
  unsigned short* attno = (unsigned short*)(ws + 58720256ull);    // 4096x2048 bf16  @56 MiB (16 MiB)
  unsigned short* vt = (unsigned short*)(ws + 75497472ull);       // 16x64x2048 bf16 @72 MiB (4 MiB)
  // total: 76 MiB

  prep<<<dim3(64, 64, 5), 256, 0, stream>>>(x, wq, wk, wv, wo, xb, wt, wot);
  // QKV GEMM over N=3072 concat [wq|wk|wv]; Q/K -> qkv (stride 2560), V -> vt transposed
  gemm_bt64<1><<<dim3(24, 32), 256, 0, stream>>>(xb, wt, qkv, 2048, 2560, vt);
  rope_k<<<4096, 256, 0, stream>>>(qkv, fcos, fsin);
  flash_attn<<<dim3(16, 32, 2), 256, 0, stream>>>(qkv, vt, fcos, fsin, attno);
  gemm_bt64<0><<<dim3(16, 32), 256, 0, stream>>>(attno, wot, d_out, 2048, 2048, nullptr);
}